// Round 1
// 1181.049 us; speedup vs baseline: 1.2180x; 1.2180x over previous
//
#include <hip/hip_runtime.h>

#define T_SEQ 2048
#define DDIM  1024
#define FDIM  4096
#define NE    8

typedef __attribute__((ext_vector_type(8))) __bf16 bf16x8;
typedef __attribute__((ext_vector_type(4))) float  f32x4;

// ---------------------------------------------------------------- async copy
__device__ __forceinline__ void gld16(const void* g, void* l) {
    __builtin_amdgcn_global_load_lds(
        (__attribute__((address_space(1))) void*)g,
        (__attribute__((address_space(3))) void*)l,
        16, 0, 0);
}

// ---------------------------------------------------------------- routing
// partial pooled sums: grid (32, 8), block 256
__global__ void kpool(const float* __restrict__ x, float* __restrict__ part) {
    int bd = blockIdx.x * 256 + threadIdx.x;     // 0..8191 = b*1024+d
    int tc = blockIdx.y;                         // 0..7
    int b = bd >> 10;
    int d = bd & 1023;
    const float* p = x + ((size_t)b * T_SEQ + (size_t)tc * 256) * DDIM + d;
    float s = 0.f;
    #pragma unroll 8
    for (int t = 0; t < 256; ++t) s += p[(size_t)t * DDIM];
    part[tc * 8192 + bd] = s;
}

// finalize routing: 1 block, 256 threads
__global__ void kroute(const float* __restrict__ part, const float* __restrict__ Wr,
                       int* __restrict__ ridx, float* __restrict__ rw) {
    __shared__ float pooled[8192];
    __shared__ float plg[256];
    __shared__ float lg[64];
    int tid = threadIdx.x;
    for (int i = tid; i < 8192; i += 256) {
        float s = 0.f;
        #pragma unroll
        for (int tc = 0; tc < 8; ++tc) s += part[tc * 8192 + i];
        pooled[i] = s * (1.0f / (float)T_SEQ);
    }
    __syncthreads();
    {
        int b = tid >> 5, e = (tid >> 2) & 7, q = tid & 3;
        float s = 0.f;
        const float* pb = pooled + b * 1024 + q * 256;
        for (int d = 0; d < 256; ++d) s += pb[d] * Wr[(q * 256 + d) * NE + e];
        plg[tid] = s;
    }
    __syncthreads();
    if (tid < 64) {
        int b = tid >> 3, e = tid & 7;
        int base = b * 32 + e * 4;
        lg[tid] = plg[base] + plg[base + 1] + plg[base + 2] + plg[base + 3];
    }
    __syncthreads();
    if (tid < 8) {
        int b = tid;
        float best = -1e30f; int bi = 0;
        #pragma unroll
        for (int e = 0; e < 8; ++e) { float v = lg[b * 8 + e]; if (v > best) { best = v; bi = e; } }
        float best2 = -1e30f; int bi2 = 0;
        #pragma unroll
        for (int e = 0; e < 8; ++e) {
            if (e == bi) continue;
            float v = lg[b * 8 + e];
            if (v > best2) { best2 = v; bi2 = e; }
        }
        float e1 = __expf(best2 - best);
        float inv = 1.0f / (1.0f + e1);
        ridx[b * 2]     = bi;
        ridx[b * 2 + 1] = bi2;
        rw[b * 2]     = inv;
        rw[b * 2 + 1] = e1 * inv;
    }
}

// ---------------------------------------------------------------- converts
// x (f32) -> bf16, 4 elements/thread
__global__ void kconvX(const float* __restrict__ in, __bf16* __restrict__ out) {
    size_t i = ((size_t)blockIdx.x * 256 + threadIdx.x) * 4;
    float4 v = *(const float4*)(in + i);
    union { __bf16 h[4]; uint2 u; } pk;
    pk.h[0] = (__bf16)v.x; pk.h[1] = (__bf16)v.y;
    pk.h[2] = (__bf16)v.z; pk.h[3] = (__bf16)v.w;
    *(uint2*)(out + i) = pk.u;
}

// transpose+convert: in (E,R,C) f32 -> out (E,C,R) bf16. grid (C/64, R/64, E)
__global__ void kconvT(const float* __restrict__ in, __bf16* __restrict__ out,
                       int R, int C) {
    __shared__ float t[64][65];
    int e  = blockIdx.z;
    int r0 = blockIdx.y * 64;
    int c0 = blockIdx.x * 64;
    int tid = threadIdx.x;
    const float* ip = in + ((size_t)e * R + r0) * C + c0;
    int tr  = tid >> 4;            // 0..15
    int tc4 = (tid & 15) * 4;      // 0..60
    #pragma unroll
    for (int j = 0; j < 4; ++j) {
        float4 v = *(const float4*)(ip + (size_t)(tr + j * 16) * C + tc4);
        t[tr + j * 16][tc4 + 0] = v.x;
        t[tr + j * 16][tc4 + 1] = v.y;
        t[tr + j * 16][tc4 + 2] = v.z;
        t[tr + j * 16][tc4 + 3] = v.w;
    }
    __syncthreads();
    __bf16* op = out + ((size_t)e * C + c0) * R + r0;
    int oc  = tid >> 2;            // 0..63 (out row = original col)
    int orb = (tid & 3) * 16;
    #pragma unroll
    for (int s = 0; s < 4; ++s) {
        int orr = orb + s * 4;
        union { __bf16 h[4]; uint2 u; } pk;
        pk.h[0] = (__bf16)t[orr + 0][oc];
        pk.h[1] = (__bf16)t[orr + 1][oc];
        pk.h[2] = (__bf16)t[orr + 2][oc];
        pk.h[3] = (__bf16)t[orr + 3][oc];
        *(uint2*)(op + (size_t)oc * R + orr) = pk.u;
    }
}

// ---------------------------------------------------------------- GEMM core
// C(256x256) += A(M x K) @ B^T(N x K), both row-major with K contiguous.
// 8 waves (2M x 4N), BK=64, double-buffered LDS (128 KiB), counted vmcnt(8)
// prefetch: next K-tile's global_load_lds stays in flight across the barrier.
// Slab layout: each 16(row)x32(k) fragment pair = one contiguous 1KB slab,
// staged via per-lane pre-swizzled global addresses -> linear LDS dest;
// fragment ds_read_b128 at base + lane*16 is conflict-free.
__device__ __forceinline__ void mma256(
    const __bf16* __restrict__ A, const __bf16* __restrict__ B, int K,
    __bf16* __restrict__ lds,      // 65536 bf16: [2 bufs][A 16384 | B 16384]
    f32x4 (&acc)[8][4], int m0, int n0)
{
    const int tid = threadIdx.x;
    const int l  = tid & 63;
    const int w  = tid >> 6;       // 0..7
    const int lr = l & 15;
    const int lq = l >> 4;
    const int wm = w >> 2;         // 0..1  -> rows [0,128)/[128,256) of tile
    const int wn = w & 3;          // 0..3  -> cols wn*64

    // each wave stages A-slabs w*4..w*4+3 and the matching B-slabs
    const __bf16* gA[4]; const __bf16* gB[4];
    int lo[4];
    #pragma unroll
    for (int i = 0; i < 4; ++i) {
        int s   = w * 4 + i;                 // slab id 0..31
        int row = ((s >> 1) << 4) + lr;      // row in tile
        int k   = ((s & 1) << 5) + (lq << 3);// k in tile
        gA[i] = A + (size_t)(m0 + row) * K + k;
        gB[i] = B + (size_t)(n0 + row) * K + k;
        lo[i] = s * 512 + l * 8;
    }

    const int nt = K >> 6;

    // prologue: stage K-tile 0 into buffer 0
    #pragma unroll
    for (int i = 0; i < 4; ++i) {
        gld16(gA[i], lds + lo[i]);
        gld16(gB[i], lds + 16384 + lo[i]);
    }

    for (int t = 0; t < nt; ++t) {
        __bf16* cur = lds + (t & 1) * 32768;
        if (t + 1 < nt) {
            __bf16* nxt = lds + ((t + 1) & 1) * 32768;
            const int koff = (t + 1) << 6;
            #pragma unroll
            for (int i = 0; i < 4; ++i) {
                gld16(gA[i] + koff, nxt + lo[i]);
                gld16(gB[i] + koff, nxt + 16384 + lo[i]);
            }
            // wait only for the CURRENT tile's 8 loads; keep next tile's 8 in flight
            asm volatile("s_waitcnt vmcnt(8)" ::: "memory");
        } else {
            asm volatile("s_waitcnt vmcnt(0)" ::: "memory");
        }
        asm volatile("s_barrier" ::: "memory");
        #pragma unroll
        for (int kk = 0; kk < 2; ++kk) {
            bf16x8 af[8], bfr[4];
            #pragma unroll
            for (int im = 0; im < 8; ++im) {
                int s = ((wm * 8 + im) << 1) + kk;
                af[im] = *(const bf16x8*)(cur + s * 512 + l * 8);
            }
            #pragma unroll
            for (int jn = 0; jn < 4; ++jn) {
                int s = ((wn * 4 + jn) << 1) + kk;
                bfr[jn] = *(const bf16x8*)(cur + 16384 + s * 512 + l * 8);
            }
            #pragma unroll
            for (int im = 0; im < 8; ++im)
                #pragma unroll
                for (int jn = 0; jn < 4; ++jn)
                    acc[im][jn] = __builtin_amdgcn_mfma_f32_16x16x32_bf16(
                        af[im], bfr[jn], acc[im][jn], 0, 0, 0);
        }
        // all ds_reads retired (lgkm waits precede MFMAs); protect buffer reuse
        asm volatile("s_barrier" ::: "memory");
    }
}

// GEMM1: h[lp] = rw[p] * gelu(x[b] @ W1t[e]^T + b1[e]), bf16 out
__global__ __launch_bounds__(512, 2) void gemm1_kernel(
    const __bf16* __restrict__ xbf, const __bf16* __restrict__ W1t,
    const float* __restrict__ b1, const int* __restrict__ ridx,
    const float* __restrict__ rw, __bf16* __restrict__ h, int p0)
{
    __shared__ __attribute__((aligned(16))) __bf16 lds[65536];
    const int lp = blockIdx.z;
    const int p  = p0 + lp;
    const int b  = p >> 1;
    const int e  = ridx[p];
    const float wgt = rw[p];
    const int m0 = blockIdx.y * 256;
    const int n0 = blockIdx.x * 256;

    f32x4 acc[8][4];
    #pragma unroll
    for (int i = 0; i < 8; ++i)
        #pragma unroll
        for (int j = 0; j < 4; ++j)
            acc[i][j] = (f32x4){0.f, 0.f, 0.f, 0.f};

    mma256(xbf + (size_t)b * T_SEQ * DDIM, W1t + (size_t)e * FDIM * DDIM,
           DDIM, lds, acc, m0, n0);

    const int l  = threadIdx.x & 63;
    const int w  = threadIdx.x >> 6;
    const int wmo = (w >> 2) << 7, wno = (w & 3) << 6;
    const int lr = l & 15, lq = l >> 4;
    __bf16* hd = h + (size_t)lp * T_SEQ * FDIM;
    const float* bias = b1 + e * FDIM;
    #pragma unroll
    for (int im = 0; im < 8; ++im) {
        int row = m0 + wmo + im * 16 + lq * 4;
        #pragma unroll
        for (int jn = 0; jn < 4; ++jn) {
            int col = n0 + wno + jn * 16 + lr;
            float bv = bias[col];
            #pragma unroll
            for (int r = 0; r < 4; ++r) {
                float v = acc[im][jn][r] + bv;
                v = 0.5f * v * (1.0f + erff(v * 0.70710678118654752f));
                hd[(size_t)(row + r) * FDIM + col] = (__bf16)(wgt * v);
            }
        }
    }
}

// GEMM2: out[s] = h[2s] @ W2t[e0]^T + h[2s+1] @ W2t[e1]^T + (w0 b2[e0] + w1 b2[e1])
__global__ __launch_bounds__(512, 2) void gemm2_kernel(
    const __bf16* __restrict__ h, const __bf16* __restrict__ W2t,
    const float* __restrict__ b2, const int* __restrict__ ridx,
    const float* __restrict__ rw, float* __restrict__ out, int s0)
{
    __shared__ __attribute__((aligned(16))) __bf16 lds[65536];
    const int ls = blockIdx.z;
    const int s  = s0 + ls;
    const int e0 = ridx[s * 2], e1 = ridx[s * 2 + 1];
    const float w0 = rw[s * 2], w1 = rw[s * 2 + 1];
    const int m0 = blockIdx.y * 256;
    const int n0 = blockIdx.x * 256;

    f32x4 acc[8][4];
    #pragma unroll
    for (int i = 0; i < 8; ++i)
        #pragma unroll
        for (int j = 0; j < 4; ++j)
            acc[i][j] = (f32x4){0.f, 0.f, 0.f, 0.f};

    mma256(h + (size_t)(2 * ls) * T_SEQ * FDIM, W2t + (size_t)e0 * DDIM * FDIM,
           FDIM, lds, acc, m0, n0);
    mma256(h + (size_t)(2 * ls + 1) * T_SEQ * FDIM, W2t + (size_t)e1 * DDIM * FDIM,
           FDIM, lds, acc, m0, n0);

    const int l  = threadIdx.x & 63;
    const int w  = threadIdx.x >> 6;
    const int wmo = (w >> 2) << 7, wno = (w & 3) << 6;
    const int lr = l & 15, lq = l >> 4;
    float* od = out + (size_t)s * T_SEQ * DDIM;
    const float* bb0 = b2 + e0 * DDIM;
    const float* bb1 = b2 + e1 * DDIM;
    #pragma unroll
    for (int im = 0; im < 8; ++im) {
        int row = m0 + wmo + im * 16 + lq * 4;
        #pragma unroll
        for (int jn = 0; jn < 4; ++jn) {
            int col = n0 + wno + jn * 16 + lr;
            float bv = w0 * bb0[col] + w1 * bb1[col];
            #pragma unroll
            for (int r = 0; r < 4; ++r)
                od[(size_t)(row + r) * DDIM + col] = acc[im][jn][r] + bv;
        }
    }
}

// ---------------------------------------------------------------- launch
extern "C" void kernel_launch(void* const* d_in, const int* in_sizes, int n_in,
                              void* d_out, int out_size, void* d_ws, size_t ws_size,
                              hipStream_t stream) {
    const float* x  = (const float*)d_in[0];
    const float* Wr = (const float*)d_in[1];
    const float* W1 = (const float*)d_in[2];
    const float* b1 = (const float*)d_in[3];
    const float* W2 = (const float*)d_in[4];
    const float* b2 = (const float*)d_in[5];
    float* out = (float*)d_out;
    char*  ws  = (char*)d_ws;

    // workspace layout (bytes)
    int*    ridx = (int*)(ws + 0);                              // 16 ints
    float*  rw   = (float*)(ws + 64);                           // 16 floats
    float*  part = (float*)(ws + 1024);                         // 8*8192 f32 = 256KB
    __bf16* xbf  = (__bf16*)(ws + ((size_t)1  << 20));          // 32MB
    __bf16* W1t  = (__bf16*)(ws + ((size_t)33 << 20));          // 64MB  (E,F,D)
    __bf16* W2t  = (__bf16*)(ws + ((size_t)97 << 20));          // 64MB  (E,D,F)
    __bf16* hbuf = (__bf16*)(ws + ((size_t)161 << 20));         // up to 256MB

    kpool <<<dim3(32, 8), 256, 0, stream>>>(x, part);
    kroute<<<1, 256, 0, stream>>>(part, Wr, ridx, rw);
    kconvX<<<16384, 256, 0, stream>>>(x, xbf);
    kconvT<<<dim3(FDIM / 64, DDIM / 64, NE), 256, 0, stream>>>(W1, W1t, DDIM, FDIM);
    kconvT<<<dim3(DDIM / 64, FDIM / 64, NE), 256, 0, stream>>>(W2, W2t, FDIM, DDIM);

    // chunk samples by available h space (32MB per sample = 2 pairs x 16MB)
    const size_t h_per_sample = (size_t)2 * T_SEQ * FDIM * sizeof(__bf16);
    size_t hcap = (ws_size > ((size_t)161 << 20)) ? ws_size - ((size_t)161 << 20) : 0;
    int csmax = (int)(hcap / h_per_sample);
    if (csmax < 1) csmax = 1;
    if (csmax > 8) csmax = 8;

    for (int smp0 = 0; smp0 < 8; smp0 += csmax) {
        int cs = (8 - smp0 < csmax) ? (8 - smp0) : csmax;
        gemm1_kernel<<<dim3(FDIM / 256, T_SEQ / 256, 2 * cs), 512, 0, stream>>>(
            xbf, W1t, b1, ridx, rw, hbuf, smp0 * 2);
        gemm2_kernel<<<dim3(DDIM / 256, T_SEQ / 256, cs), 512, 0, stream>>>(
            hbuf, W2t, b2, ridx, rw, out, smp0);
    }
}

// Round 2
// 1072.461 us; speedup vs baseline: 1.3413x; 1.1013x over previous
//
#include <hip/hip_runtime.h>

#define T_SEQ 2048
#define DDIM  1024
#define FDIM  4096
#define NE    8

typedef __attribute__((ext_vector_type(8))) __bf16 bf16x8;
typedef __attribute__((ext_vector_type(4))) float  f32x4;

// ---------------------------------------------------------------- async copy
__device__ __forceinline__ void gld16(const void* g, void* l) {
    __builtin_amdgcn_global_load_lds(
        (__attribute__((address_space(1))) void*)g,
        (__attribute__((address_space(3))) void*)l,
        16, 0, 0);
}

// ---------------------------------------------------------------- routing
// partial pooled sums: grid (32, 8), block 256
__global__ void kpool(const float* __restrict__ x, float* __restrict__ part) {
    int bd = blockIdx.x * 256 + threadIdx.x;     // 0..8191 = b*1024+d
    int tc = blockIdx.y;                         // 0..7
    int b = bd >> 10;
    int d = bd & 1023;
    const float* p = x + ((size_t)b * T_SEQ + (size_t)tc * 256) * DDIM + d;
    float s = 0.f;
    #pragma unroll 8
    for (int t = 0; t < 256; ++t) s += p[(size_t)t * DDIM];
    part[tc * 8192 + bd] = s;
}

// finalize routing: 1 block, 256 threads
__global__ void kroute(const float* __restrict__ part, const float* __restrict__ Wr,
                       int* __restrict__ ridx, float* __restrict__ rw) {
    __shared__ float pooled[8192];
    __shared__ float plg[256];
    __shared__ float lg[64];
    int tid = threadIdx.x;
    for (int i = tid; i < 8192; i += 256) {
        float s = 0.f;
        #pragma unroll
        for (int tc = 0; tc < 8; ++tc) s += part[tc * 8192 + i];
        pooled[i] = s * (1.0f / (float)T_SEQ);
    }
    __syncthreads();
    {
        int b = tid >> 5, e = (tid >> 2) & 7, q = tid & 3;
        float s = 0.f;
        const float* pb = pooled + b * 1024 + q * 256;
        for (int d = 0; d < 256; ++d) s += pb[d] * Wr[(q * 256 + d) * NE + e];
        plg[tid] = s;
    }
    __syncthreads();
    if (tid < 64) {
        int b = tid >> 3, e = tid & 7;
        int base = b * 32 + e * 4;
        lg[tid] = plg[base] + plg[base + 1] + plg[base + 2] + plg[base + 3];
    }
    __syncthreads();
    if (tid < 8) {
        int b = tid;
        float best = -1e30f; int bi = 0;
        #pragma unroll
        for (int e = 0; e < 8; ++e) { float v = lg[b * 8 + e]; if (v > best) { best = v; bi = e; } }
        float best2 = -1e30f; int bi2 = 0;
        #pragma unroll
        for (int e = 0; e < 8; ++e) {
            if (e == bi) continue;
            float v = lg[b * 8 + e];
            if (v > best2) { best2 = v; bi2 = e; }
        }
        float e1 = __expf(best2 - best);
        float inv = 1.0f / (1.0f + e1);
        ridx[b * 2]     = bi;
        ridx[b * 2 + 1] = bi2;
        rw[b * 2]     = inv;
        rw[b * 2 + 1] = e1 * inv;
    }
}

// ---------------------------------------------------------------- converts
// x (f32) -> bf16, 4 elements/thread
__global__ void kconvX(const float* __restrict__ in, __bf16* __restrict__ out) {
    size_t i = ((size_t)blockIdx.x * 256 + threadIdx.x) * 4;
    float4 v = *(const float4*)(in + i);
    union { __bf16 h[4]; uint2 u; } pk;
    pk.h[0] = (__bf16)v.x; pk.h[1] = (__bf16)v.y;
    pk.h[2] = (__bf16)v.z; pk.h[3] = (__bf16)v.w;
    *(uint2*)(out + i) = pk.u;
}

// transpose+convert: in (E,R,C) f32 -> out (E,C,R) bf16. grid (C/64, R/64, E)
__global__ void kconvT(const float* __restrict__ in, __bf16* __restrict__ out,
                       int R, int C) {
    __shared__ float t[64][65];
    int e  = blockIdx.z;
    int r0 = blockIdx.y * 64;
    int c0 = blockIdx.x * 64;
    int tid = threadIdx.x;
    const float* ip = in + ((size_t)e * R + r0) * C + c0;
    int tr  = tid >> 4;            // 0..15
    int tc4 = (tid & 15) * 4;      // 0..60
    #pragma unroll
    for (int j = 0; j < 4; ++j) {
        float4 v = *(const float4*)(ip + (size_t)(tr + j * 16) * C + tc4);
        t[tr + j * 16][tc4 + 0] = v.x;
        t[tr + j * 16][tc4 + 1] = v.y;
        t[tr + j * 16][tc4 + 2] = v.z;
        t[tr + j * 16][tc4 + 3] = v.w;
    }
    __syncthreads();
    __bf16* op = out + ((size_t)e * C + c0) * R + r0;
    int oc  = tid >> 2;            // 0..63 (out row = original col)
    int orb = (tid & 3) * 16;
    #pragma unroll
    for (int s = 0; s < 4; ++s) {
        int orr = orb + s * 4;
        union { __bf16 h[4]; uint2 u; } pk;
        pk.h[0] = (__bf16)t[orr + 0][oc];
        pk.h[1] = (__bf16)t[orr + 1][oc];
        pk.h[2] = (__bf16)t[orr + 2][oc];
        pk.h[3] = (__bf16)t[orr + 3][oc];
        *(uint2*)(op + (size_t)oc * R + orr) = pk.u;
    }
}

// ---------------------------------------------------------------- GEMM core
// C(256x256) += A(M x K) @ B^T(N x K), both row-major with K contiguous.
// m201-style 4-phase/K-tile schedule: per phase {ds_read subtile || issue 2
// global_load_lds -> s_barrier -> lgkmcnt(0) -> setprio(1) 16xMFMA setprio(0)
// -> s_barrier}. Counted vmcnt(4) once per K-tile (never 0 in steady state).
// Slab layout: each 16(row)x32(k) fragment = one contiguous 1KB slab, staged
// via per-lane global addresses -> linear LDS; ds_read_b128 at base + lane*16
// is conflict-free.
// Prefetch stream (quarters of 4 loads... 2 gld16/thread each):
//   phase 0: A rows 0..127  of tile t+1   (buffer ^1)
//   phase 1: A rows 128..255 of tile t+1  (buffer ^1)
//   phase 2: B rows 0..127  of tile t+2   (buffer  =, B read-drained @phase 0)
//   phase 3: B rows 128..255 of tile t+2
// end of phase 3: vmcnt(4) drains tile t+1 (12 -> 4 outstanding).
template<int K>
__device__ __forceinline__ void mma256(
    const __bf16* __restrict__ A, const __bf16* __restrict__ B,
    __bf16* __restrict__ lds,      // 65536 bf16: [2 bufs][A 16384 | B 16384]
    f32x4 (&acc)[8][4], int m0, int n0)
{
    constexpr int nt = K >> 6;
    const int tid = threadIdx.x;
    const int l  = tid & 63;
    const int w  = tid >> 6;       // 0..7
    const int lr = l & 15;
    const int lq = l >> 4;
    const int wm = w >> 2;         // 0..1 -> rows [0,128)/[128,256)
    const int wn = w & 3;          // 0..3 -> cols wn*64

    // staging addresses: wave w stages slabs {2w, 2w+1} of each quarter.
    // slab 2w+j: rows w*16+lr, k-half j  (j<<5 + lq*8)
    long aoff[2], boff[2];
    int  lA[2],  lB[2];
    #pragma unroll
    for (int j = 0; j < 2; ++j) {
        aoff[j] = (long)(m0 + (w << 4) + lr) * K + (j << 5) + (lq << 3);
        boff[j] = (long)(n0 + (w << 4) + lr) * K + (j << 5) + (lq << 3);
        lA[j] = (2 * w + j) * 512 + l * 8;
        lB[j] = 16384 + (2 * w + j) * 512 + l * 8;
    }
    const long rhalf = (long)128 * K;           // +128 rows (high quarter)

    // fragment ds_read element-offsets: A slab (wm*8+rb)*2+kk, B slab (wn*4+jn)*2+kk
    const int afo = wm * 8 * 1024 + l * 8;      // + rb*1024 + kk*512
    const int bfo = 16384 + wn * 4 * 1024 + l * 8;

    // ---------------- prologue: tile 0 (8 loads) + tile 1 B quarters (4 loads)
    #pragma unroll
    for (int j = 0; j < 2; ++j) {
        gld16(A + aoff[j],         lds + lA[j]);
        gld16(A + aoff[j] + rhalf, lds + lA[j] + 8192);
        gld16(B + boff[j],         lds + lB[j]);
        gld16(B + boff[j] + rhalf, lds + lB[j] + 8192);
    }
    if (nt > 1) {
        __bf16* d1 = lds + 32768;
        #pragma unroll
        for (int j = 0; j < 2; ++j) {
            gld16(B + boff[j] + 64,         d1 + lB[j]);
            gld16(B + boff[j] + rhalf + 64, d1 + lB[j] + 8192);
        }
        asm volatile("s_waitcnt vmcnt(4)" ::: "memory");
    } else {
        asm volatile("s_waitcnt vmcnt(0)" ::: "memory");
    }
    __builtin_amdgcn_s_barrier();

    bf16x8 bfr[4][2];
    for (int t = 0; t < nt; ++t) {
        const __bf16* cur = lds + (t & 1) * 32768;
        __bf16* nx1 = lds + ((t + 1) & 1) * 32768;   // buffer of tile t+1
        __bf16* nx2 = lds + (t & 1) * 32768;         // buffer of tile t+2
        const long ko1 = (long)(t + 1) << 6;
        const long ko2 = (long)(t + 2) << 6;

        bf16x8 af[2][2];

        // ================= phase 0: A rb0,1 + all B reads; stage A-low(t+1)
        #pragma unroll
        for (int kk = 0; kk < 2; ++kk) {
            af[0][kk] = *(const bf16x8*)(cur + afo + 0 * 1024 + kk * 512);
            af[1][kk] = *(const bf16x8*)(cur + afo + 1 * 1024 + kk * 512);
            #pragma unroll
            for (int jn = 0; jn < 4; ++jn)
                bfr[jn][kk] = *(const bf16x8*)(cur + bfo + jn * 1024 + kk * 512);
        }
        if (t + 1 < nt) {
            #pragma unroll
            for (int j = 0; j < 2; ++j)
                gld16(A + aoff[j] + ko1, nx1 + lA[j]);
        }
        __builtin_amdgcn_s_barrier();
        asm volatile("s_waitcnt lgkmcnt(0)" ::: "memory");
        __builtin_amdgcn_sched_barrier(0);
        __builtin_amdgcn_s_setprio(1);
        #pragma unroll
        for (int kk = 0; kk < 2; ++kk)
            #pragma unroll
            for (int jn = 0; jn < 4; ++jn) {
                acc[0][jn] = __builtin_amdgcn_mfma_f32_16x16x32_bf16(af[0][kk], bfr[jn][kk], acc[0][jn], 0, 0, 0);
                acc[1][jn] = __builtin_amdgcn_mfma_f32_16x16x32_bf16(af[1][kk], bfr[jn][kk], acc[1][jn], 0, 0, 0);
            }
        __builtin_amdgcn_s_setprio(0);
        __builtin_amdgcn_s_barrier();

        // ================= phase 1: A rb2,3; stage A-high(t+1)
        #pragma unroll
        for (int kk = 0; kk < 2; ++kk) {
            af[0][kk] = *(const bf16x8*)(cur + afo + 2 * 1024 + kk * 512);
            af[1][kk] = *(const bf16x8*)(cur + afo + 3 * 1024 + kk * 512);
        }
        if (t + 1 < nt) {
            #pragma unroll
            for (int j = 0; j < 2; ++j)
                gld16(A + aoff[j] + rhalf + ko1, nx1 + lA[j] + 8192);
        }
        __builtin_amdgcn_s_barrier();
        asm volatile("s_waitcnt lgkmcnt(0)" ::: "memory");
        __builtin_amdgcn_sched_barrier(0);
        __builtin_amdgcn_s_setprio(1);
        #pragma unroll
        for (int kk = 0; kk < 2; ++kk)
            #pragma unroll
            for (int jn = 0; jn < 4; ++jn) {
                acc[2][jn] = __builtin_amdgcn_mfma_f32_16x16x32_bf16(af[0][kk], bfr[jn][kk], acc[2][jn], 0, 0, 0);
                acc[3][jn] = __builtin_amdgcn_mfma_f32_16x16x32_bf16(af[1][kk], bfr[jn][kk], acc[3][jn], 0, 0, 0);
            }
        __builtin_amdgcn_s_setprio(0);
        __builtin_amdgcn_s_barrier();

        // ================= phase 2: A rb4,5; stage B-low(t+2)
        #pragma unroll
        for (int kk = 0; kk < 2; ++kk) {
            af[0][kk] = *(const bf16x8*)(cur + afo + 4 * 1024 + kk * 512);
            af[1][kk] = *(const bf16x8*)(cur + afo + 5 * 1024 + kk * 512);
        }
        if (t + 2 < nt) {
            #pragma unroll
            for (int j = 0; j < 2; ++j)
                gld16(B + boff[j] + ko2, nx2 + lB[j]);
        }
        __builtin_amdgcn_s_barrier();
        asm volatile("s_waitcnt lgkmcnt(0)" ::: "memory");
        __builtin_amdgcn_sched_barrier(0);
        __builtin_amdgcn_s_setprio(1);
        #pragma unroll
        for (int kk = 0; kk < 2; ++kk)
            #pragma unroll
            for (int jn = 0; jn < 4; ++jn) {
                acc[4][jn] = __builtin_amdgcn_mfma_f32_16x16x32_bf16(af[0][kk], bfr[jn][kk], acc[4][jn], 0, 0, 0);
                acc[5][jn] = __builtin_amdgcn_mfma_f32_16x16x32_bf16(af[1][kk], bfr[jn][kk], acc[5][jn], 0, 0, 0);
            }
        __builtin_amdgcn_s_setprio(0);
        __builtin_amdgcn_s_barrier();

        // ================= phase 3: A rb6,7; stage B-high(t+2); tile-end wait
        #pragma unroll
        for (int kk = 0; kk < 2; ++kk) {
            af[0][kk] = *(const bf16x8*)(cur + afo + 6 * 1024 + kk * 512);
            af[1][kk] = *(const bf16x8*)(cur + afo + 7 * 1024 + kk * 512);
        }
        if (t + 2 < nt) {
            #pragma unroll
            for (int j = 0; j < 2; ++j)
                gld16(B + boff[j] + rhalf + ko2, nx2 + lB[j] + 8192);
        }
        __builtin_amdgcn_s_barrier();
        asm volatile("s_waitcnt lgkmcnt(0)" ::: "memory");
        __builtin_amdgcn_sched_barrier(0);
        __builtin_amdgcn_s_setprio(1);
        #pragma unroll
        for (int kk = 0; kk < 2; ++kk)
            #pragma unroll
            for (int jn = 0; jn < 4; ++jn) {
                acc[6][jn] = __builtin_amdgcn_mfma_f32_16x16x32_bf16(af[0][kk], bfr[jn][kk], acc[6][jn], 0, 0, 0);
                acc[7][jn] = __builtin_amdgcn_mfma_f32_16x16x32_bf16(af[1][kk], bfr[jn][kk], acc[7][jn], 0, 0, 0);
            }
        __builtin_amdgcn_s_setprio(0);
        if (t + 1 < nt) {
            if (t + 2 < nt) asm volatile("s_waitcnt vmcnt(4)" ::: "memory");
            else            asm volatile("s_waitcnt vmcnt(0)" ::: "memory");
        }
        __builtin_amdgcn_s_barrier();
    }
}

// GEMM1: h[lp] = rw[p] * gelu(x[b] @ W1t[e]^T + b1[e]), bf16 out
__global__ __launch_bounds__(512, 2) void gemm1_kernel(
    const __bf16* __restrict__ xbf, const __bf16* __restrict__ W1t,
    const float* __restrict__ b1, const int* __restrict__ ridx,
    const float* __restrict__ rw, __bf16* __restrict__ h, int p0)
{
    __shared__ __attribute__((aligned(16))) __bf16 lds[65536];
    const int lp = blockIdx.z;
    const int p  = p0 + lp;
    const int b  = p >> 1;
    const int e  = ridx[p];
    const float wgt = rw[p];
    const int m0 = blockIdx.y * 256;
    const int n0 = blockIdx.x * 256;

    f32x4 acc[8][4];
    #pragma unroll
    for (int i = 0; i < 8; ++i)
        #pragma unroll
        for (int j = 0; j < 4; ++j)
            acc[i][j] = (f32x4){0.f, 0.f, 0.f, 0.f};

    mma256<DDIM>(xbf + (size_t)b * T_SEQ * DDIM, W1t + (size_t)e * FDIM * DDIM,
                 lds, acc, m0, n0);

    const int l  = threadIdx.x & 63;
    const int w  = threadIdx.x >> 6;
    const int wmo = (w >> 2) << 7, wno = (w & 3) << 6;
    const int lr = l & 15, lq = l >> 4;
    __bf16* hd = h + (size_t)lp * T_SEQ * FDIM;
    const float* bias = b1 + e * FDIM;
    #pragma unroll
    for (int im = 0; im < 8; ++im) {
        int row = m0 + wmo + im * 16 + lq * 4;
        #pragma unroll
        for (int jn = 0; jn < 4; ++jn) {
            int col = n0 + wno + jn * 16 + lr;
            float bv = bias[col];
            #pragma unroll
            for (int r = 0; r < 4; ++r) {
                float v = acc[im][jn][r] + bv;
                v = 0.5f * v * (1.0f + erff(v * 0.70710678118654752f));
                hd[(size_t)(row + r) * FDIM + col] = (__bf16)(wgt * v);
            }
        }
    }
}

// GEMM2: out[s] = h[2s] @ W2t[e0]^T + h[2s+1] @ W2t[e1]^T + (w0 b2[e0] + w1 b2[e1])
__global__ __launch_bounds__(512, 2) void gemm2_kernel(
    const __bf16* __restrict__ h, const __bf16* __restrict__ W2t,
    const float* __restrict__ b2, const int* __restrict__ ridx,
    const float* __restrict__ rw, float* __restrict__ out, int s0)
{
    __shared__ __attribute__((aligned(16))) __bf16 lds[65536];
    const int ls = blockIdx.z;
    const int s  = s0 + ls;
    const int e0 = ridx[s * 2], e1 = ridx[s * 2 + 1];
    const float w0 = rw[s * 2], w1 = rw[s * 2 + 1];
    const int m0 = blockIdx.y * 256;
    const int n0 = blockIdx.x * 256;

    f32x4 acc[8][4];
    #pragma unroll
    for (int i = 0; i < 8; ++i)
        #pragma unroll
        for (int j = 0; j < 4; ++j)
            acc[i][j] = (f32x4){0.f, 0.f, 0.f, 0.f};

    mma256<FDIM>(h + (size_t)(2 * ls) * T_SEQ * FDIM, W2t + (size_t)e0 * DDIM * FDIM,
                 lds, acc, m0, n0);
    mma256<FDIM>(h + (size_t)(2 * ls + 1) * T_SEQ * FDIM, W2t + (size_t)e1 * DDIM * FDIM,
                 lds, acc, m0, n0);

    const int l  = threadIdx.x & 63;
    const int w  = threadIdx.x >> 6;
    const int wmo = (w >> 2) << 7, wno = (w & 3) << 6;
    const int lr = l & 15, lq = l >> 4;
    float* od = out + (size_t)s * T_SEQ * DDIM;
    const float* bb0 = b2 + e0 * DDIM;
    const float* bb1 = b2 + e1 * DDIM;
    #pragma unroll
    for (int im = 0; im < 8; ++im) {
        int row = m0 + wmo + im * 16 + lq * 4;
        #pragma unroll
        for (int jn = 0; jn < 4; ++jn) {
            int col = n0 + wno + jn * 16 + lr;
            float bv = w0 * bb0[col] + w1 * bb1[col];
            #pragma unroll
            for (int r = 0; r < 4; ++r)
                od[(size_t)(row + r) * DDIM + col] = acc[im][jn][r] + bv;
        }
    }
}

// ---------------------------------------------------------------- launch
extern "C" void kernel_launch(void* const* d_in, const int* in_sizes, int n_in,
                              void* d_out, int out_size, void* d_ws, size_t ws_size,
                              hipStream_t stream) {
    const float* x  = (const float*)d_in[0];
    const float* Wr = (const float*)d_in[1];
    const float* W1 = (const float*)d_in[2];
    const float* b1 = (const float*)d_in[3];
    const float* W2 = (const float*)d_in[4];
    const float* b2 = (const float*)d_in[5];
    float* out = (float*)d_out;
    char*  ws  = (char*)d_ws;

    // workspace layout (bytes)
    int*    ridx = (int*)(ws + 0);                              // 16 ints
    float*  rw   = (float*)(ws + 64);                           // 16 floats
    float*  part = (float*)(ws + 1024);                         // 8*8192 f32 = 256KB
    __bf16* xbf  = (__bf16*)(ws + ((size_t)1  << 20));          // 32MB
    __bf16* W1t  = (__bf16*)(ws + ((size_t)33 << 20));          // 64MB  (E,F,D)
    __bf16* W2t  = (__bf16*)(ws + ((size_t)97 << 20));          // 64MB  (E,D,F)
    __bf16* hbuf = (__bf16*)(ws + ((size_t)161 << 20));         // up to 256MB

    kpool <<<dim3(32, 8), 256, 0, stream>>>(x, part);
    kroute<<<1, 256, 0, stream>>>(part, Wr, ridx, rw);
    kconvX<<<16384, 256, 0, stream>>>(x, xbf);
    kconvT<<<dim3(FDIM / 64, DDIM / 64, NE), 256, 0, stream>>>(W1, W1t, DDIM, FDIM);
    kconvT<<<dim3(DDIM / 64, FDIM / 64, NE), 256, 0, stream>>>(W2, W2t, FDIM, DDIM);

    // chunk samples by available h space (32MB per sample = 2 pairs x 16MB)
    const size_t h_per_sample = (size_t)2 * T_SEQ * FDIM * sizeof(__bf16);
    size_t hcap = (ws_size > ((size_t)161 << 20)) ? ws_size - ((size_t)161 << 20) : 0;
    int csmax = (int)(hcap / h_per_sample);
    if (csmax < 1) csmax = 1;
    if (csmax > 8) csmax = 8;

    for (int smp0 = 0; smp0 < 8; smp0 += csmax) {
        int cs = (8 - smp0 < csmax) ? (8 - smp0) : csmax;
        gemm1_kernel<<<dim3(FDIM / 256, T_SEQ / 256, 2 * cs), 512, 0, stream>>>(
            xbf, W1t, b1, ridx, rw, hbuf, smp0 * 2);
        gemm2_kernel<<<dim3(DDIM / 256, T_SEQ / 256, cs), 512, 0, stream>>>(
            hbuf, W2t, b2, ridx, rw, out, smp0);
    }
}

// Round 3
// 1060.152 us; speedup vs baseline: 1.3569x; 1.0116x over previous
//
#include <hip/hip_runtime.h>

#define T_SEQ 2048
#define DDIM  1024
#define FDIM  4096
#define NE    8

typedef __attribute__((ext_vector_type(8))) __bf16 bf16x8;
typedef __attribute__((ext_vector_type(4))) float  f32x4;

// ---------------------------------------------------------------- async copy
__device__ __forceinline__ void gld16(const void* g, void* l) {
    __builtin_amdgcn_global_load_lds(
        (__attribute__((address_space(1))) void*)g,
        (__attribute__((address_space(3))) void*)l,
        16, 0, 0);
}

// bijective XCD-chunked swizzle (requires nblk % 8 == 0): HW round-robins
// blockIdx across 8 XCDs; remap so each XCD owns a contiguous chunk.
__device__ __forceinline__ int xcd_swz(int bid, int nblk) {
    int chunk = nblk >> 3;
    return (bid & 7) * chunk + (bid >> 3);
}

// ---------------------------------------------------------------- routing
// partial pooled sums: grid (32, 8), block 256
__global__ void kpool(const float* __restrict__ x, float* __restrict__ part) {
    int bd = blockIdx.x * 256 + threadIdx.x;     // 0..8191 = b*1024+d
    int tc = blockIdx.y;                         // 0..7
    int b = bd >> 10;
    int d = bd & 1023;
    const float* p = x + ((size_t)b * T_SEQ + (size_t)tc * 256) * DDIM + d;
    float s = 0.f;
    #pragma unroll 8
    for (int t = 0; t < 256; ++t) s += p[(size_t)t * DDIM];
    part[tc * 8192 + bd] = s;
}

// finalize routing: 1 block, 256 threads
__global__ void kroute(const float* __restrict__ part, const float* __restrict__ Wr,
                       int* __restrict__ ridx, float* __restrict__ rw) {
    __shared__ float pooled[8192];
    __shared__ float plg[256];
    __shared__ float lg[64];
    int tid = threadIdx.x;
    for (int i = tid; i < 8192; i += 256) {
        float s = 0.f;
        #pragma unroll
        for (int tc = 0; tc < 8; ++tc) s += part[tc * 8192 + i];
        pooled[i] = s * (1.0f / (float)T_SEQ);
    }
    __syncthreads();
    {
        int b = tid >> 5, e = (tid >> 2) & 7, q = tid & 3;
        float s = 0.f;
        const float* pb = pooled + b * 1024 + q * 256;
        for (int d = 0; d < 256; ++d) s += pb[d] * Wr[(q * 256 + d) * NE + e];
        plg[tid] = s;
    }
    __syncthreads();
    if (tid < 64) {
        int b = tid >> 3, e = tid & 7;
        int base = b * 32 + e * 4;
        lg[tid] = plg[base] + plg[base + 1] + plg[base + 2] + plg[base + 3];
    }
    __syncthreads();
    if (tid < 8) {
        int b = tid;
        float best = -1e30f; int bi = 0;
        #pragma unroll
        for (int e = 0; e < 8; ++e) { float v = lg[b * 8 + e]; if (v > best) { best = v; bi = e; } }
        float best2 = -1e30f; int bi2 = 0;
        #pragma unroll
        for (int e = 0; e < 8; ++e) {
            if (e == bi) continue;
            float v = lg[b * 8 + e];
            if (v > best2) { best2 = v; bi2 = e; }
        }
        float e1 = __expf(best2 - best);
        float inv = 1.0f / (1.0f + e1);
        ridx[b * 2]     = bi;
        ridx[b * 2 + 1] = bi2;
        rw[b * 2]     = inv;
        rw[b * 2 + 1] = e1 * inv;
    }
}

// ---------------------------------------------------------------- converts
// x (f32) -> bf16, 4 elements/thread
__global__ void kconvX(const float* __restrict__ in, __bf16* __restrict__ out) {
    size_t i = ((size_t)blockIdx.x * 256 + threadIdx.x) * 4;
    float4 v = *(const float4*)(in + i);
    union { __bf16 h[4]; uint2 u; } pk;
    pk.h[0] = (__bf16)v.x; pk.h[1] = (__bf16)v.y;
    pk.h[2] = (__bf16)v.z; pk.h[3] = (__bf16)v.w;
    *(uint2*)(out + i) = pk.u;
}

// transpose+convert: in (E,R,C) f32 -> out (E,C,R) bf16. grid (C/64, R/64, E)
__global__ void kconvT(const float* __restrict__ in, __bf16* __restrict__ out,
                       int R, int C) {
    __shared__ float t[64][65];
    int e  = blockIdx.z;
    int r0 = blockIdx.y * 64;
    int c0 = blockIdx.x * 64;
    int tid = threadIdx.x;
    const float* ip = in + ((size_t)e * R + r0) * C + c0;
    int tr  = tid >> 4;            // 0..15
    int tc4 = (tid & 15) * 4;      // 0..60
    #pragma unroll
    for (int j = 0; j < 4; ++j) {
        float4 v = *(const float4*)(ip + (size_t)(tr + j * 16) * C + tc4);
        t[tr + j * 16][tc4 + 0] = v.x;
        t[tr + j * 16][tc4 + 1] = v.y;
        t[tr + j * 16][tc4 + 2] = v.z;
        t[tr + j * 16][tc4 + 3] = v.w;
    }
    __syncthreads();
    __bf16* op = out + ((size_t)e * C + c0) * R + r0;
    int oc  = tid >> 2;            // 0..63 (out row = original col)
    int orb = (tid & 3) * 16;
    #pragma unroll
    for (int s = 0; s < 4; ++s) {
        int orr = orb + s * 4;
        union { __bf16 h[4]; uint2 u; } pk;
        pk.h[0] = (__bf16)t[orr + 0][oc];
        pk.h[1] = (__bf16)t[orr + 1][oc];
        pk.h[2] = (__bf16)t[orr + 2][oc];
        pk.h[3] = (__bf16)t[orr + 3][oc];
        *(uint2*)(op + (size_t)oc * R + orr) = pk.u;
    }
}

// ---------------------------------------------------------------- GEMM core
// C(256x256) += A(M x K) @ B^T(N x K), both row-major with K contiguous.
// 4-phase/K-tile schedule, balanced reads 8/8/4/4:
//   P0: read A rb0-3 kk0 + B jn0-3 kk0 ; stage A-low(t+1)  -> MFMA rb0-3 kk0
//   P1: read A rb4-7 kk0 + B jn0-3 kk1 ; stage A-high(t+1) -> MFMA rb4-7 kk0
//   P2: read A rb0-3 kk1               ; stage B-low(t+2)  -> MFMA rb0-3 kk1
//   P3: read A rb4-7 kk1               ; stage B-high(t+2) -> MFMA rb4-7 kk1
// Counted vmcnt(4) once per K-tile (never 0 in steady state). Slab layout:
// each 16(row)x32(k) fragment = one contiguous 1KB slab, per-lane global
// addresses -> linear LDS; ds_read_b128 at base + lane*16 is conflict-free.
template<int K>
__device__ __forceinline__ void mma256(
    const __bf16* __restrict__ A, const __bf16* __restrict__ B,
    __bf16* __restrict__ lds,      // 65536 bf16: [2 bufs][A 16384 | B 16384]
    f32x4 (&acc)[8][4], int m0, int n0)
{
    constexpr int nt = K >> 6;
    const int tid = threadIdx.x;
    const int l  = tid & 63;
    const int w  = tid >> 6;       // 0..7
    const int lr = l & 15;
    const int lq = l >> 4;
    const int wm = w >> 2;         // 0..1 -> rows [0,128)/[128,256)
    const int wn = w & 3;          // 0..3 -> cols wn*64

    // staging addresses: wave w stages slabs {2w, 2w+1} of each quarter.
    long aoff[2], boff[2];
    int  lA[2],  lB[2];
    #pragma unroll
    for (int j = 0; j < 2; ++j) {
        aoff[j] = (long)(m0 + (w << 4) + lr) * K + (j << 5) + (lq << 3);
        boff[j] = (long)(n0 + (w << 4) + lr) * K + (j << 5) + (lq << 3);
        lA[j] = (2 * w + j) * 512 + l * 8;
        lB[j] = 16384 + (2 * w + j) * 512 + l * 8;
    }
    const long rhalf = (long)128 * K;           // +128 rows (high quarter)

    // fragment ds_read element-offsets
    const int afo = wm * 8 * 1024 + l * 8;      // + rb*1024 + kk*512
    const int bfo = 16384 + wn * 4 * 1024 + l * 8;

    // ---------------- prologue: tile 0 (8 loads) + tile 1 B quarters (4 loads)
    #pragma unroll
    for (int j = 0; j < 2; ++j) {
        gld16(A + aoff[j],         lds + lA[j]);
        gld16(A + aoff[j] + rhalf, lds + lA[j] + 8192);
        gld16(B + boff[j],         lds + lB[j]);
        gld16(B + boff[j] + rhalf, lds + lB[j] + 8192);
    }
    if (nt > 1) {
        __bf16* d1 = lds + 32768;
        #pragma unroll
        for (int j = 0; j < 2; ++j) {
            gld16(B + boff[j] + 64,         d1 + lB[j]);
            gld16(B + boff[j] + rhalf + 64, d1 + lB[j] + 8192);
        }
        asm volatile("s_waitcnt vmcnt(4)" ::: "memory");
    } else {
        asm volatile("s_waitcnt vmcnt(0)" ::: "memory");
    }
    __builtin_amdgcn_s_barrier();

    bf16x8 bfr[4][2];
    for (int t = 0; t < nt; ++t) {
        const __bf16* cur = lds + (t & 1) * 32768;
        __bf16* nx1 = lds + ((t + 1) & 1) * 32768;   // buffer of tile t+1
        __bf16* nx2 = lds + (t & 1) * 32768;         // buffer of tile t+2
        const long ko1 = (long)(t + 1) << 6;
        const long ko2 = (long)(t + 2) << 6;

        bf16x8 af[4];

        // ================= P0: A rb0-3 kk0 + B kk0; stage A-low(t+1)
        #pragma unroll
        for (int i = 0; i < 4; ++i)
            af[i] = *(const bf16x8*)(cur + afo + i * 1024);
        #pragma unroll
        for (int jn = 0; jn < 4; ++jn)
            bfr[jn][0] = *(const bf16x8*)(cur + bfo + jn * 1024);
        if (t + 1 < nt) {
            #pragma unroll
            for (int j = 0; j < 2; ++j)
                gld16(A + aoff[j] + ko1, nx1 + lA[j]);
        }
        __builtin_amdgcn_s_barrier();
        asm volatile("s_waitcnt lgkmcnt(0)" ::: "memory");
        __builtin_amdgcn_sched_barrier(0);
        __builtin_amdgcn_s_setprio(1);
        #pragma unroll
        for (int i = 0; i < 4; ++i)
            #pragma unroll
            for (int jn = 0; jn < 4; ++jn)
                acc[i][jn] = __builtin_amdgcn_mfma_f32_16x16x32_bf16(af[i], bfr[jn][0], acc[i][jn], 0, 0, 0);
        __builtin_amdgcn_s_setprio(0);
        __builtin_amdgcn_s_barrier();

        // ================= P1: A rb4-7 kk0 + B kk1; stage A-high(t+1)
        #pragma unroll
        for (int i = 0; i < 4; ++i)
            af[i] = *(const bf16x8*)(cur + afo + (4 + i) * 1024);
        #pragma unroll
        for (int jn = 0; jn < 4; ++jn)
            bfr[jn][1] = *(const bf16x8*)(cur + bfo + jn * 1024 + 512);
        if (t + 1 < nt) {
            #pragma unroll
            for (int j = 0; j < 2; ++j)
                gld16(A + aoff[j] + rhalf + ko1, nx1 + lA[j] + 8192);
        }
        __builtin_amdgcn_s_barrier();
        asm volatile("s_waitcnt lgkmcnt(0)" ::: "memory");
        __builtin_amdgcn_sched_barrier(0);
        __builtin_amdgcn_s_setprio(1);
        #pragma unroll
        for (int i = 0; i < 4; ++i)
            #pragma unroll
            for (int jn = 0; jn < 4; ++jn)
                acc[4 + i][jn] = __builtin_amdgcn_mfma_f32_16x16x32_bf16(af[i], bfr[jn][0], acc[4 + i][jn], 0, 0, 0);
        __builtin_amdgcn_s_setprio(0);
        __builtin_amdgcn_s_barrier();

        // ================= P2: A rb0-3 kk1; stage B-low(t+2)
        #pragma unroll
        for (int i = 0; i < 4; ++i)
            af[i] = *(const bf16x8*)(cur + afo + i * 1024 + 512);
        if (t + 2 < nt) {
            #pragma unroll
            for (int j = 0; j < 2; ++j)
                gld16(B + boff[j] + ko2, nx2 + lB[j]);
        }
        __builtin_amdgcn_s_barrier();
        asm volatile("s_waitcnt lgkmcnt(0)" ::: "memory");
        __builtin_amdgcn_sched_barrier(0);
        __builtin_amdgcn_s_setprio(1);
        #pragma unroll
        for (int i = 0; i < 4; ++i)
            #pragma unroll
            for (int jn = 0; jn < 4; ++jn)
                acc[i][jn] = __builtin_amdgcn_mfma_f32_16x16x32_bf16(af[i], bfr[jn][1], acc[i][jn], 0, 0, 0);
        __builtin_amdgcn_s_setprio(0);
        __builtin_amdgcn_s_barrier();

        // ================= P3: A rb4-7 kk1; stage B-high(t+2); tile-end wait
        #pragma unroll
        for (int i = 0; i < 4; ++i)
            af[i] = *(const bf16x8*)(cur + afo + (4 + i) * 1024 + 512);
        if (t + 2 < nt) {
            #pragma unroll
            for (int j = 0; j < 2; ++j)
                gld16(B + boff[j] + rhalf + ko2, nx2 + lB[j] + 8192);
        }
        __builtin_amdgcn_s_barrier();
        asm volatile("s_waitcnt lgkmcnt(0)" ::: "memory");
        __builtin_amdgcn_sched_barrier(0);
        __builtin_amdgcn_s_setprio(1);
        #pragma unroll
        for (int i = 0; i < 4; ++i)
            #pragma unroll
            for (int jn = 0; jn < 4; ++jn)
                acc[4 + i][jn] = __builtin_amdgcn_mfma_f32_16x16x32_bf16(af[i], bfr[jn][1], acc[4 + i][jn], 0, 0, 0);
        __builtin_amdgcn_s_setprio(0);
        if (t + 1 < nt) {
            if (t + 2 < nt) asm volatile("s_waitcnt vmcnt(4)" ::: "memory");
            else            asm volatile("s_waitcnt vmcnt(0)" ::: "memory");
        }
        __builtin_amdgcn_s_barrier();
    }
}

// GEMM1: h[lp] = rw[p] * gelu(x[b] @ W1t[e]^T + b1[e]), bf16 out. 1D grid.
__global__ __launch_bounds__(512, 2) void gemm1_kernel(
    const __bf16* __restrict__ xbf, const __bf16* __restrict__ W1t,
    const float* __restrict__ b1, const int* __restrict__ ridx,
    const float* __restrict__ rw, __bf16* __restrict__ h, int p0)
{
    __shared__ __attribute__((aligned(16))) __bf16 lds[65536];
    const int sb = xcd_swz(blockIdx.x, gridDim.x);
    const int bx = sb & 15;          // FDIM/256
    const int by = (sb >> 4) & 7;    // T_SEQ/256
    const int lp = sb >> 7;
    const int p  = p0 + lp;
    const int b  = p >> 1;
    const int e  = ridx[p];
    const float wgt = rw[p];
    const int m0 = by * 256;
    const int n0 = bx * 256;

    f32x4 acc[8][4];
    #pragma unroll
    for (int i = 0; i < 8; ++i)
        #pragma unroll
        for (int j = 0; j < 4; ++j)
            acc[i][j] = (f32x4){0.f, 0.f, 0.f, 0.f};

    mma256<DDIM>(xbf + (size_t)b * T_SEQ * DDIM, W1t + (size_t)e * FDIM * DDIM,
                 lds, acc, m0, n0);

    const int l  = threadIdx.x & 63;
    const int w  = threadIdx.x >> 6;
    const int wmo = (w >> 2) << 7, wno = (w & 3) << 6;
    const int lr = l & 15, lq = l >> 4;
    __bf16* hd = h + (size_t)lp * T_SEQ * FDIM;
    const float* bias = b1 + e * FDIM;
    #pragma unroll
    for (int im = 0; im < 8; ++im) {
        int row = m0 + wmo + im * 16 + lq * 4;
        #pragma unroll
        for (int jn = 0; jn < 4; ++jn) {
            int col = n0 + wno + jn * 16 + lr;
            float bv = bias[col];
            #pragma unroll
            for (int r = 0; r < 4; ++r) {
                float v = acc[im][jn][r] + bv;
                v = 0.5f * v * (1.0f + erff(v * 0.70710678118654752f));
                hd[(size_t)(row + r) * FDIM + col] = (__bf16)(wgt * v);
            }
        }
    }
}

// GEMM2: out[s] = h[2s] @ W2t[e0]^T + h[2s+1] @ W2t[e1]^T + bias. 1D grid.
__global__ __launch_bounds__(512, 2) void gemm2_kernel(
    const __bf16* __restrict__ h, const __bf16* __restrict__ W2t,
    const float* __restrict__ b2, const int* __restrict__ ridx,
    const float* __restrict__ rw, float* __restrict__ out, int s0)
{
    __shared__ __attribute__((aligned(16))) __bf16 lds[65536];
    const int sb = xcd_swz(blockIdx.x, gridDim.x);
    const int bx = sb & 3;           // DDIM/256
    const int by = (sb >> 2) & 7;    // T_SEQ/256
    const int ls = sb >> 5;
    const int s  = s0 + ls;
    const int e0 = ridx[s * 2], e1 = ridx[s * 2 + 1];
    const float w0 = rw[s * 2], w1 = rw[s * 2 + 1];
    const int m0 = by * 256;
    const int n0 = bx * 256;

    f32x4 acc[8][4];
    #pragma unroll
    for (int i = 0; i < 8; ++i)
        #pragma unroll
        for (int j = 0; j < 4; ++j)
            acc[i][j] = (f32x4){0.f, 0.f, 0.f, 0.f};

    mma256<FDIM>(h + (size_t)(2 * ls) * T_SEQ * FDIM, W2t + (size_t)e0 * DDIM * FDIM,
                 lds, acc, m0, n0);
    mma256<FDIM>(h + (size_t)(2 * ls + 1) * T_SEQ * FDIM, W2t + (size_t)e1 * DDIM * FDIM,
                 lds, acc, m0, n0);

    const int l  = threadIdx.x & 63;
    const int w  = threadIdx.x >> 6;
    const int wmo = (w >> 2) << 7, wno = (w & 3) << 6;
    const int lr = l & 15, lq = l >> 4;
    float* od = out + (size_t)s * T_SEQ * DDIM;
    const float* bb0 = b2 + e0 * DDIM;
    const float* bb1 = b2 + e1 * DDIM;
    #pragma unroll
    for (int im = 0; im < 8; ++im) {
        int row = m0 + wmo + im * 16 + lq * 4;
        #pragma unroll
        for (int jn = 0; jn < 4; ++jn) {
            int col = n0 + wno + jn * 16 + lr;
            float bv = w0 * bb0[col] + w1 * bb1[col];
            #pragma unroll
            for (int r = 0; r < 4; ++r)
                od[(size_t)(row + r) * DDIM + col] = acc[im][jn][r] + bv;
        }
    }
}

// ---------------------------------------------------------------- launch
extern "C" void kernel_launch(void* const* d_in, const int* in_sizes, int n_in,
                              void* d_out, int out_size, void* d_ws, size_t ws_size,
                              hipStream_t stream) {
    const float* x  = (const float*)d_in[0];
    const float* Wr = (const float*)d_in[1];
    const float* W1 = (const float*)d_in[2];
    const float* b1 = (const float*)d_in[3];
    const float* W2 = (const float*)d_in[4];
    const float* b2 = (const float*)d_in[5];
    float* out = (float*)d_out;
    char*  ws  = (char*)d_ws;

    // workspace layout (bytes)
    int*    ridx = (int*)(ws + 0);                              // 16 ints
    float*  rw   = (float*)(ws + 64);                           // 16 floats
    float*  part = (float*)(ws + 1024);                         // 8*8192 f32 = 256KB
    __bf16* xbf  = (__bf16*)(ws + ((size_t)1  << 20));          // 32MB
    __bf16* W1t  = (__bf16*)(ws + ((size_t)33 << 20));          // 64MB  (E,F,D)
    __bf16* W2t  = (__bf16*)(ws + ((size_t)97 << 20));          // 64MB  (E,D,F)
    __bf16* hbuf = (__bf16*)(ws + ((size_t)161 << 20));         // up to 256MB

    kpool <<<dim3(32, 8), 256, 0, stream>>>(x, part);
    kroute<<<1, 256, 0, stream>>>(part, Wr, ridx, rw);
    kconvX<<<16384, 256, 0, stream>>>(x, xbf);
    kconvT<<<dim3(FDIM / 64, DDIM / 64, NE), 256, 0, stream>>>(W1, W1t, DDIM, FDIM);
    kconvT<<<dim3(DDIM / 64, FDIM / 64, NE), 256, 0, stream>>>(W2, W2t, FDIM, DDIM);

    // chunk samples by available h space (32MB per sample = 2 pairs x 16MB)
    const size_t h_per_sample = (size_t)2 * T_SEQ * FDIM * sizeof(__bf16);
    size_t hcap = (ws_size > ((size_t)161 << 20)) ? ws_size - ((size_t)161 << 20) : 0;
    int csmax = (int)(hcap / h_per_sample);
    if (csmax < 1) csmax = 1;
    if (csmax > 8) csmax = 8;

    for (int smp0 = 0; smp0 < 8; smp0 += csmax) {
        int cs = (8 - smp0 < csmax) ? (8 - smp0) : csmax;
        gemm1_kernel<<<16 * 8 * 2 * cs, 512, 0, stream>>>(
            xbf, W1t, b1, ridx, rw, hbuf, smp0 * 2);
        gemm2_kernel<<<4 * 8 * cs, 512, 0, stream>>>(
            hbuf, W2t, b2, ridx, rw, out, smp0);
    }
}